// Round 1
// 198.841 us; speedup vs baseline: 1.0026x; 1.0026x over previous
//
#include <hip/hip_runtime.h>

#define INF_DELTA 1e10f
#define LOG2E 1.4426950408889634f
#define LOG2_EPS -33.219280948873623f   // log2(1e-10)

// DPP helper: returns src permuted by CTRL; lanes not written (row_mask) or
// reading out-of-bounds produce 0 (old=0) — the additive identity.
template<int CTRL, int RMASK>
__device__ __forceinline__ float dpp0(float v) {
    return __int_as_float(
        __builtin_amdgcn_update_dpp(0, __float_as_int(v), CTRL, RMASK, 0xF, false));
}

// Canonical gfx9 wave64 inclusive add-scan: 6 full-rate DPP ops, no LDS pipe.
__device__ __forceinline__ float wave_incl_scan_add(float v) {
    v += dpp0<0x111, 0xF>(v);  // row_shr:1
    v += dpp0<0x112, 0xF>(v);  // row_shr:2
    v += dpp0<0x114, 0xF>(v);  // row_shr:4
    v += dpp0<0x118, 0xF>(v);  // row_shr:8
    v += dpp0<0x142, 0xA>(v);  // row_bcast:15 -> rows 1,3
    v += dpp0<0x143, 0xC>(v);  // row_bcast:31 -> rows 2,3
    return v;
}

// One 64-lane wave per ray; lane s owns sample s.
__global__ __launch_bounds__(256) void raymarch_kernel(
    const float* __restrict__ colors,      // (n_rays, 64, 3)
    const float* __restrict__ densities,   // (n_rays, 64)
    const float* __restrict__ depths,      // (n_rays, 64)
    float* __restrict__ rgb_out,           // (n_rays, 3)
    float* __restrict__ depth_out,         // (n_rays,)
    float* __restrict__ weights_out,       // (n_rays, 64)
    float* __restrict__ trans_out,         // (n_rays,)
    int n_rays)
{
    const int lane = threadIdx.x & 63;
    const int ray  = blockIdx.x * 4 + (threadIdx.x >> 6);
    if (ray >= n_rays) return;

    const long base = (long)ray * 64 + lane;

    // Coalesced loads. d_next via overlapping load (L1 hit) instead of a
    // ds-shuffle so both issue back-to-back and latencies overlap.
    const float d      = depths[base];
    const float d_next = depths[base + ((lane < 63) ? 1 : 0)];
    const float x      = densities[base];
    const float3 c     = *reinterpret_cast<const float3*>(colors + (long)ray * 192 + lane * 3);

    const float delta = (lane == 63) ? INF_DELTA : (d_next - d);

    // log2-domain softplus: log2(1+e^x) = relu(x)*log2e + log2(1 + exp2(-|x|*log2e))
    const float q   = __builtin_amdgcn_exp2f(-__builtin_fabsf(x) * LOG2E);
    const float l2  = __builtin_amdgcn_logf(1.0f + q);          // log2(1+q)
    const float sp2 = __builtin_fmaf(__builtin_fmaxf(x, 0.0f), LOG2E, l2);
    const float g   = -delta * sp2;                             // log2(y)
    const float y   = __builtin_amdgcn_exp2f(g);
    const float alpha = 1.0f - y;

    // log2(y + 1e-10) ~= max(g, log2(1e-10)); error confined to trans <= 2e-10.
    const float llane = __builtin_fmaxf(g, LOG2_EPS);

    // cumprod -> exp2(cumsum): DPP scan replaces 6 dependent ds_bpermutes.
    const float S          = wave_incl_scan_add(llane);   // inclusive
    const float trans_excl = __builtin_amdgcn_exp2f(S - llane);

    const float w = alpha * trans_excl;
    weights_out[base] = w;   // coalesced

    // 4-value reduction: quad sums via DPP quad_perm, cross-quad via row_ror,
    // then only 2 LDS-pipe ops (xor16 swizzle + xor32 shuffle).
    float s0 = w * c.x, s1 = w * c.y, s2 = w * c.z, s3 = w * d;
    s0 += dpp0<0xB1, 0xF>(s0);  // quad_perm [1,0,3,2]
    s1 += dpp0<0xB1, 0xF>(s1);
    s2 += dpp0<0xB1, 0xF>(s2);
    s3 += dpp0<0xB1, 0xF>(s3);
    s0 += dpp0<0x4E, 0xF>(s0);  // quad_perm [2,3,0,1]
    s1 += dpp0<0x4E, 0xF>(s1);
    s2 += dpp0<0x4E, 0xF>(s2);
    s3 += dpp0<0x4E, 0xF>(s3);

    const int sel = lane & 3;
    float v = (sel == 0) ? s0 : (sel == 1) ? s1 : (sel == 2) ? s2 : s3;
    v += dpp0<0x124, 0xF>(v);   // row_ror:4  (preserves lane&3, crosses quads)
    v += dpp0<0x128, 0xF>(v);   // row_ror:8
    v += __int_as_float(__builtin_amdgcn_ds_swizzle(__float_as_int(v), 0x401F)); // xor16
    v += __shfl_xor(v, 32, 64); // cross-half

    if (lane < 3) {
        rgb_out[(long)ray * 3 + lane] = v;
    } else if (lane == 3) {
        depth_out[ray] = v;
    } else if (lane == 63) {
        trans_out[ray] = __builtin_amdgcn_exp2f(S);   // inclusive total = finalT
    }
}

extern "C" void kernel_launch(void* const* d_in, const int* in_sizes, int n_in,
                              void* d_out, int out_size, void* d_ws, size_t ws_size,
                              hipStream_t stream) {
    const float* colors    = (const float*)d_in[0];
    const float* densities = (const float*)d_in[1];
    const float* depths    = (const float*)d_in[2];

    const int n_rays = in_sizes[1] / 64;   // densities flat count = n_rays * 64

    float* out      = (float*)d_out;
    float* rgb      = out;                              // n_rays*3
    float* depth_o  = rgb + (long)n_rays * 3;           // n_rays
    float* weights  = depth_o + n_rays;                 // n_rays*64
    float* trans    = weights + (long)n_rays * 64;      // n_rays

    const int blocks = (n_rays + 3) / 4;   // 4 waves (rays) per 256-thread block
    raymarch_kernel<<<blocks, 256, 0, stream>>>(
        colors, densities, depths, rgb, depth_o, weights, trans, n_rays);
}